// Round 2
// baseline (21541.335 us; speedup 1.0000x reference)
//
#include <hip/hip_runtime.h>

typedef unsigned int u32;
typedef unsigned short u16;
typedef __attribute__((ext_vector_type(8))) short bf16x8;
typedef __attribute__((ext_vector_type(4))) float f32x4;

#define MFMA16(a, b, c) __builtin_amdgcn_mfma_f32_16x16x32_bf16((a), (b), (c), 0, 0, 0)

__device__ __forceinline__ float bf2f(u16 h) {
  union { u32 u; float f; } x; x.u = ((u32)h) << 16; return x.f;
}
__device__ __forceinline__ u16 f2bf(float f) {
  union { float f; u32 u; } x; x.f = f;
  u32 r = (x.u + 0x7FFFu + ((x.u >> 16) & 1u)) >> 16;
  return (u16)r;
}
__device__ __forceinline__ float sigm(float x) { return 1.0f / (1.0f + __expf(-x)); }
__device__ __forceinline__ float tanh_(float x) {
  float e = __expf(2.0f * x);
  return 1.0f - 2.0f / (e + 1.0f);   // safe at +/-inf
}

__global__ void sentinelK(float* __restrict__ out) {
  if (threadIdx.x == 0) out[0] = 1.0e6f;   // "workspace too small" marker
}

// ---------------- mask dtype sniffing + pooled masks ----------------
__global__ void modeK(const unsigned char* __restrict__ m, int* __restrict__ mode) {
  if (threadIdx.x == 0) *mode = (m[1] | m[2]) ? 1 : 4;  // 1 = bool bytes, 4 = int32
}

__device__ __forceinline__ bool rawmask(const void* mp, int md, int b, int t) {
  if (md == 1) return ((const unsigned char*)mp)[b * 1696 + t] != 0;
  return ((const int*)mp)[b * 1696 + t] != 0;
}

__global__ __launch_bounds__(256) void maskK(
    const void* __restrict__ m, const int* __restrict__ mode,
    unsigned char* __restrict__ m0, unsigned char* __restrict__ m1,
    unsigned char* __restrict__ m2, unsigned char* __restrict__ m3,
    float* __restrict__ outMask) {
  int idx = blockIdx.x * 256 + threadIdx.x;  // 54272
  int t = idx >> 5, b = idx & 31;
  int md = *mode;
  m0[t * 32 + b] = rawmask(m, md, b, t) ? 1 : 0;
  if (t < 848) {
    bool a = rawmask(m, md, b, 2 * t) && rawmask(m, md, b, 2 * t + 1);
    m1[t * 32 + b] = a ? 1 : 0;
  }
  if (t < 424) {
    bool a = true;
    for (int j = 0; j < 4; ++j) a = a && rawmask(m, md, b, 4 * t + j);
    m2[t * 32 + b] = a ? 1 : 0;
  }
  if (t < 212) {
    bool a = true;
    for (int j = 0; j < 8; ++j) a = a && rawmask(m, md, b, 8 * t + j);
    m3[t * 32 + b] = a ? 1 : 0;
    outMask[b * 212 + t] = a ? 1.0f : 0.0f;
  }
}

// ---------------- positional encoding table (double, matches np.float64 ref) ----
__global__ __launch_bounds__(256) void petK(float* __restrict__ pet) {
  int idx = blockIdx.x * 256 + threadIdx.x;  // 1696*512
  int t = idx >> 9, d = idx & 511;
  double e = (double)((d >> 1) * 2) / 512.0;
  double freq = exp(e * -9.210340371976184);  // 10000^-e
  double ang = (double)t * freq;
  double vv = (d & 1) ? cos(ang) : sin(ang);
  pet[idx] = (float)vv;
}

// ---------------- weight packing: (K,N) fp32 -> (N,K) bf16 ----------------
__global__ __launch_bounds__(256) void packW(const float* __restrict__ src,
                                             u16* __restrict__ dst, int ksh, int N) {
  int idx = blockIdx.x * 256 + threadIdx.x;  // over N*K
  int n = idx >> ksh;
  int k = idx & ((1 << ksh) - 1);
  dst[idx] = f2bf(src[(size_t)k * N + n]);
}

__global__ void biasK(const float* __restrict__ fb, const float* __restrict__ bb,
                      float* __restrict__ dst) {
  int i = blockIdx.x * 256 + threadIdx.x;  // 2048
  dst[i] = (i < 1024) ? fb[i] : bb[i - 1024];
}

// ---------------- chunked mel projection + scale + pet -> xc [2][Cl][32][512] bf16 --
__global__ __launch_bounds__(256) void x0cK(
    const float* __restrict__ inp, const float* __restrict__ dw,
    const float* __restrict__ db, const float* __restrict__ scale,
    const float* __restrict__ pet, u16* __restrict__ xc,
    int t0f, int t0b, int Cl) {
  const int bid = blockIdx.x;          // 2*Cl
  const int d = (bid >= Cl) ? 1 : 0;
  const int lt = bid - d * Cl;
  const int t = (d ? t0b : t0f) + lt;
  __shared__ float xin[32][40];
  for (int i = threadIdx.x; i < 1280; i += 256) {
    int b = i / 40, k = i - b * 40;
    xin[b][k] = inp[((size_t)b * 1696 + t) * 40 + k];
  }
  __syncthreads();
  const float sc = 71.554175279993267f * scale[0];
  for (int dd = threadIdx.x; dd < 512; dd += 256) {
    float w[40];
#pragma unroll
    for (int k = 0; k < 40; ++k) w[k] = dw[k * 512 + dd];
    const float pv = pet[t * 512 + dd];
    const float bv = db[dd];
    u16* out = xc + (((size_t)d * Cl + lt) * 32) * 512 + dd;
    for (int b = 0; b < 32; ++b) {
      float acc = bv;
#pragma unroll
      for (int k = 0; k < 40; ++k) acc += xin[b][k] * w[k];
      out[(size_t)b * 512] = f2bf(acc * sc + pv);
    }
  }
}

// ---------------- xz chunk GEMM: per dir, [Cl*32][K] @ [K][1024] + bias -> f32 ----
// A rows contiguous from Af/Ab; Wp: [2][1024][K] bf16 (n,k); out: [2][Cl][32][1024] f32
__global__ __launch_bounds__(256) void gemmK(
    const u16* __restrict__ Af, const u16* __restrict__ Ab,
    const u16* __restrict__ Wp, const float* __restrict__ bias,
    float* __restrict__ out, int K, int Cl) {
  __shared__ u16 As[64 * 72];
  __shared__ u16 Bs[128 * 72];
  const int tid = threadIdx.x;
  const int bm = blockIdx.x, bn = blockIdx.y, d = blockIdx.z;
  const u16* A = d ? Ab : Af;
  const u16* W = Wp + (size_t)d * (size_t)K * 1024;
  const int w = tid >> 6, L = tid & 63, ln = L & 15, q = L >> 4;
  const int wm = w & 1, wn = w >> 1;

  f32x4 acc[2][4];
#pragma unroll
  for (int mt = 0; mt < 2; ++mt)
#pragma unroll
    for (int nt = 0; nt < 4; ++nt) acc[mt][nt] = (f32x4){0.f, 0.f, 0.f, 0.f};

  const int arow = tid >> 2, akc = (tid & 3) * 16;
  const int brow = tid >> 1, bkc = (tid & 1) * 32;
  const u16* Xp = A + (size_t)(bm * 64 + arow) * K + akc;
  const u16* Bp = W + (size_t)(bn * 128 + brow) * K + bkc;

  for (int kt = 0; kt < K; kt += 64) {
    uint4 av0 = *(const uint4*)(Xp + kt);
    uint4 av1 = *(const uint4*)(Xp + kt + 8);
    uint4 bv0 = *(const uint4*)(Bp + kt);
    uint4 bv1 = *(const uint4*)(Bp + kt + 8);
    uint4 bv2 = *(const uint4*)(Bp + kt + 16);
    uint4 bv3 = *(const uint4*)(Bp + kt + 24);
    *(uint4*)&As[arow * 72 + akc] = av0;
    *(uint4*)&As[arow * 72 + akc + 8] = av1;
    *(uint4*)&Bs[brow * 72 + bkc] = bv0;
    *(uint4*)&Bs[brow * 72 + bkc + 8] = bv1;
    *(uint4*)&Bs[brow * 72 + bkc + 16] = bv2;
    *(uint4*)&Bs[brow * 72 + bkc + 24] = bv3;
    __syncthreads();
#pragma unroll
    for (int ks = 0; ks < 2; ++ks) {
      bf16x8 a0 = *(const bf16x8*)&As[(wm * 32 + ln) * 72 + ks * 32 + q * 8];
      bf16x8 a1 = *(const bf16x8*)&As[(wm * 32 + 16 + ln) * 72 + ks * 32 + q * 8];
      bf16x8 b0 = *(const bf16x8*)&Bs[(wn * 64 + ln) * 72 + ks * 32 + q * 8];
      bf16x8 b1 = *(const bf16x8*)&Bs[(wn * 64 + 16 + ln) * 72 + ks * 32 + q * 8];
      bf16x8 b2 = *(const bf16x8*)&Bs[(wn * 64 + 32 + ln) * 72 + ks * 32 + q * 8];
      bf16x8 b3 = *(const bf16x8*)&Bs[(wn * 64 + 48 + ln) * 72 + ks * 32 + q * 8];
      acc[0][0] = MFMA16(a0, b0, acc[0][0]);
      acc[0][1] = MFMA16(a0, b1, acc[0][1]);
      acc[0][2] = MFMA16(a0, b2, acc[0][2]);
      acc[0][3] = MFMA16(a0, b3, acc[0][3]);
      acc[1][0] = MFMA16(a1, b0, acc[1][0]);
      acc[1][1] = MFMA16(a1, b1, acc[1][1]);
      acc[1][2] = MFMA16(a1, b2, acc[1][2]);
      acc[1][3] = MFMA16(a1, b3, acc[1][3]);
    }
    __syncthreads();
  }
  float* outd = out + (size_t)d * Cl * 32768;
#pragma unroll
  for (int nt = 0; nt < 4; ++nt) {
    const int col = bn * 128 + wn * 64 + nt * 16 + ln;
    const float bv = bias[d * 1024 + col];
#pragma unroll
    for (int mt = 0; mt < 2; ++mt) {
      const size_t rb = (size_t)(bm * 64 + wm * 32 + mt * 16 + q * 4) * 1024 + col;
#pragma unroll
      for (int r = 0; r < 4; ++r) outd[rb + (size_t)r * 1024] = acc[mt][nt][r] + bv;
    }
  }
}

// ---------------- persistent bidirectional LSTM recurrence (chunked) ----------------
// 16 blocks x 256 thr: blocks 0..7 = fw (column-split), 8..15 = bw.
// Wr wave-resident; h exchange via double-buffered global ring + flag barrier.
__global__ __launch_bounds__(256) void recK(
    const float* __restrict__ xz,     // [2][Cl][32][1024] f32
    const u16* __restrict__ WrP,      // [2][1024][256] bf16 (n,k)
    u16* __restrict__ hbufL,          // [2 dir][2 buf][32][256] bf16, pre-zeroed once
    float* __restrict__ cbuf,         // [2 dir][32][256] f32
    int* __restrict__ flags,          // [2 dir][1696], pre-zeroed once
    const unsigned char* __restrict__ msk,  // [T][32]
    u16* __restrict__ Xnext,          // [T/2][32][1024] bf16 (non-final)
    float* __restrict__ outH,         // [32][T][512] f32 (final)
    int T, int Cl, int s0, int isFinal) {
  const int tid = threadIdx.x;
  const int dir = blockIdx.x >> 3;
  const int wg = blockIdx.x & 7;
  const int v = tid >> 6;
  const int L = tid & 63;
  const int ln = L & 15;
  const int q = L >> 4;
  const bool low = (ln & 8) == 0;
  const int ug = wg * 32 + v * 8 + (ln & 7);  // this lane's hidden unit

  __shared__ u16 A_lds[32 * 264];

  // Wr fragments, register-resident for the whole chunk.
  bf16x8 bfr[2][8];
  {
    const u16* wr = WrP + (size_t)dir * 262144;
#pragma unroll
    for (int nt = 0; nt < 2; ++nt) {
      const int n = (nt * 2 + (ln >> 3)) * 256 + ug;  // gate-major column
#pragma unroll
      for (int ks = 0; ks < 8; ++ks)
        bfr[nt][ks] = *(const bf16x8*)(wr + (size_t)n * 256 + ks * 32 + q * 8);
    }
  }

  int* flg = flags + dir * 1696;
  float* cb = cbuf + dir * 8192;

  float cst[2][4];
  if (s0 == 0) {
#pragma unroll
    for (int mt = 0; mt < 2; ++mt)
#pragma unroll
      for (int r = 0; r < 4; ++r) cst[mt][r] = 0.f;
  } else {
#pragma unroll
    for (int mt = 0; mt < 2; ++mt)
#pragma unroll
      for (int r = 0; r < 4; ++r)
        cst[mt][r] = cb[(mt * 16 + q * 4 + r) * 256 + ug];
  }

  for (int s = s0; s < s0 + Cl; ++s) {
    const int t = dir ? (T - 1 - s) : s;
    const int lt = dir ? (s0 + Cl - 1 - s) : (s - s0);

    // prefetch xz (fp32, own gate columns) + mask for this t
    float xzv[2][2][4];
    const float* xzt = xz + ((size_t)dir * Cl + lt) * 32768;
#pragma unroll
    for (int nt = 0; nt < 2; ++nt) {
      const int ncol = (nt * 2 + (ln >> 3)) * 256 + ug;
#pragma unroll
      for (int mt = 0; mt < 2; ++mt)
#pragma unroll
        for (int r = 0; r < 4; ++r)
          xzv[mt][nt][r] = xzt[(size_t)(mt * 16 + q * 4 + r) * 1024 + ncol];
    }
    unsigned char mkv[2][4];
#pragma unroll
    for (int mt = 0; mt < 2; ++mt)
#pragma unroll
      for (int r = 0; r < 4; ++r) mkv[mt][r] = msk[t * 32 + mt * 16 + q * 4 + r];

    // wait for all 8 producers (this direction) of step s-1
    if (s > 0) {
      if (tid == 0) {
        while (__hip_atomic_load(&flg[s - 1], __ATOMIC_ACQUIRE, __HIP_MEMORY_SCOPE_AGENT) < 8)
          __builtin_amdgcn_s_sleep(1);
      }
      __syncthreads();
    }

    // stage h(s-1) (buffer (s+1)&1) into LDS, agent-scope loads bypass stale caches
    {
      u32* hsrc = (u32*)(hbufL + dir * 16384 + ((s + 1) & 1) * 8192);
      const int mrow = tid >> 3, cc = tid & 7;
#pragma unroll
      for (int g2 = 0; g2 < 4; ++g2) {
        const int bidx = mrow * 128 + cc * 16 + g2 * 4;
        u32 u0 = __hip_atomic_load(hsrc + bidx + 0, __ATOMIC_RELAXED, __HIP_MEMORY_SCOPE_AGENT);
        u32 u1 = __hip_atomic_load(hsrc + bidx + 1, __ATOMIC_RELAXED, __HIP_MEMORY_SCOPE_AGENT);
        u32 u2 = __hip_atomic_load(hsrc + bidx + 2, __ATOMIC_RELAXED, __HIP_MEMORY_SCOPE_AGENT);
        u32 u3 = __hip_atomic_load(hsrc + bidx + 3, __ATOMIC_RELAXED, __HIP_MEMORY_SCOPE_AGENT);
        uint4 val; val.x = u0; val.y = u1; val.z = u2; val.w = u3;
        *(uint4*)&A_lds[mrow * 264 + cc * 32 + g2 * 8] = val;
      }
    }
    __syncthreads();

    f32x4 acc[2][2];
#pragma unroll
    for (int mt = 0; mt < 2; ++mt)
#pragma unroll
      for (int nt = 0; nt < 2; ++nt) acc[mt][nt] = (f32x4){0.f, 0.f, 0.f, 0.f};

#pragma unroll
    for (int ks = 0; ks < 8; ++ks) {
      bf16x8 a0 = *(const bf16x8*)&A_lds[ln * 264 + ks * 32 + q * 8];
      bf16x8 a1 = *(const bf16x8*)&A_lds[(16 + ln) * 264 + ks * 32 + q * 8];
      acc[0][0] = MFMA16(a0, bfr[0][ks], acc[0][0]);
      acc[0][1] = MFMA16(a0, bfr[1][ks], acc[0][1]);
      acc[1][0] = MFMA16(a1, bfr[0][ks], acc[1][0]);
      acc[1][1] = MFMA16(a1, bfr[1][ks], acc[1][1]);
    }

    float hsv[2][4];
#pragma unroll
    for (int mt = 0; mt < 2; ++mt) {
#pragma unroll
      for (int r = 0; r < 4; ++r) {
        float z0 = acc[mt][0][r] + xzv[mt][0][r];  // i (low half) / f (high half)
        float z1 = acc[mt][1][r] + xzv[mt][1][r];  // g / o
        float z0p = __shfl_xor(z0, 8);
        float z1p = __shfl_xor(z1, 8);
        float iv = low ? z0 : z0p;
        float fv = low ? z0p : z0;
        float gv = low ? z1 : z1p;
        float ov = low ? z1p : z1;
        float cold = cst[mt][r];
        float cn = sigm(fv) * cold + sigm(iv) * tanh_(gv);
        float hn = sigm(ov) * tanh_(cn);
        const int m = mt * 16 + q * 4 + r;
        float hold = bf2f(A_lds[m * 264 + ug]);
        bool mb = mkv[mt][r] != 0;
        cst[mt][r] = mb ? cn : cold;
        float hs = mb ? hn : hold;
        hsv[mt][r] = hs;
        if (low) {
          if (isFinal)
            outH[((size_t)m * T + t) * 512 + dir * 256 + ug] = hs;
          else
            Xnext[((size_t)(t >> 1) * 32 + m) * 1024 + (t & 1) * 512 + dir * 256 + ug] =
                f2bf(hs);
        }
      }
    }

    // pack adjacent units into u32 and publish h(s) to buffer (s&1)
    {
      u32* hdst = (u32*)(hbufL + dir * 16384 + (s & 1) * 8192);
#pragma unroll
      for (int mt = 0; mt < 2; ++mt) {
#pragma unroll
        for (int r = 0; r < 4; ++r) {
          u32 lo = (u32)f2bf(hsv[mt][r]);
          u32 par = (u32)__shfl_xor((int)lo, 1);
          u32 val = lo | (par << 16);
          if (low && ((ln & 1) == 0)) {
            const int m = mt * 16 + q * 4 + r;
            __hip_atomic_store(hdst + m * 128 + (ug >> 1), val,
                               __ATOMIC_RELAXED, __HIP_MEMORY_SCOPE_AGENT);
          }
        }
      }
    }

    __syncthreads();  // drains vmem: all stores done before release
    if (tid == 0)
      __hip_atomic_fetch_add(&flg[s], 1, __ATOMIC_RELEASE, __HIP_MEMORY_SCOPE_AGENT);
  }

  // persist c for the next chunk
  if (low) {
#pragma unroll
    for (int mt = 0; mt < 2; ++mt)
#pragma unroll
      for (int r = 0; r < 4; ++r)
        cb[(mt * 16 + q * 4 + r) * 256 + ug] = cst[mt][r];
  }
}

// ---------------- host ----------------
extern "C" void kernel_launch(void* const* d_in, const int* in_sizes, int n_in,
                              void* d_out, int out_size, void* d_ws, size_t ws_size,
                              hipStream_t stream) {
  char* ws = (char*)d_ws;
  constexpr size_t O_PET   = 0;                    // 3,473,408
  constexpr size_t O_WK    = 3473408;              // 14,680,064
  constexpr size_t O_BIAS  = O_WK + 14680064;      // 32,768
  constexpr size_t O_WR    = O_BIAS + 32768;       // 4,194,304
  constexpr size_t O_M0    = O_WR + 4194304;       // 54,272
  constexpr size_t O_M1    = O_M0 + 54272;         // 27,136
  constexpr size_t O_M2    = O_M1 + 27136;         // 13,568
  constexpr size_t O_M3    = O_M2 + 13568;         // 6,784
  constexpr size_t O_MODE  = O_M3 + 6784;          // 256
  constexpr size_t O_FLAGS = O_MODE + 256;         // 54,272
  constexpr size_t O_HBUF  = O_FLAGS + 54272;      // 262,144
  constexpr size_t O_CBUF  = O_HBUF + 262144;      // 262,144
  constexpr size_t O_XB0   = O_CBUF + 262144;      // 55,574,528
  constexpr size_t O_XB1   = O_XB0 + 55574528;     // 27,787,264
  constexpr size_t O_XC    = O_XB1 + 27787264;     // = 106,422,912

  int C = 0;
  if      (ws_size >= O_XC + 848ull * 327680) C = 848;
  else if (ws_size >= O_XC + 424ull * 327680) C = 424;
  else if (ws_size >= O_XC + 212ull * 327680) C = 212;
  else if (ws_size >= O_XC + 106ull * 327680) C = 106;
  if (C == 0) { sentinelK<<<1, 64, 0, stream>>>((float*)d_out); return; }

  hipMemsetAsync(ws + O_FLAGS, 0, 54272 + 262144, stream);  // flags + hbuf

  modeK<<<1, 64, 0, stream>>>((const unsigned char*)d_in[1], (int*)(ws + O_MODE));
  maskK<<<212, 256, 0, stream>>>(d_in[1], (const int*)(ws + O_MODE),
                                 (unsigned char*)(ws + O_M0), (unsigned char*)(ws + O_M1),
                                 (unsigned char*)(ws + O_M2), (unsigned char*)(ws + O_M3),
                                 (float*)d_out + 3473408);
  petK<<<3392, 256, 0, stream>>>((float*)(ws + O_PET));

  u16* wk = (u16*)(ws + O_WK);
  u16* wrp = (u16*)(ws + O_WR);
  float* bias = (float*)(ws + O_BIAS);
  // Wk: (din,1024) -> (1024,din) bf16, fw then bw per layer
  packW<<<2048, 256, 0, stream>>>((const float*)d_in[5],  wk + 0,       9, 1024);
  packW<<<2048, 256, 0, stream>>>((const float*)d_in[8],  wk + 524288,  9, 1024);
  packW<<<4096, 256, 0, stream>>>((const float*)d_in[11], wk + 1048576, 10, 1024);
  packW<<<4096, 256, 0, stream>>>((const float*)d_in[14], wk + 2097152, 10, 1024);
  packW<<<4096, 256, 0, stream>>>((const float*)d_in[17], wk + 3145728, 10, 1024);
  packW<<<4096, 256, 0, stream>>>((const float*)d_in[20], wk + 4194304, 10, 1024);
  packW<<<4096, 256, 0, stream>>>((const float*)d_in[23], wk + 5242880, 10, 1024);
  packW<<<4096, 256, 0, stream>>>((const float*)d_in[26], wk + 6291456, 10, 1024);
  // Wr: (256,1024) -> (1024,256) bf16
  packW<<<1024, 256, 0, stream>>>((const float*)d_in[6],  wrp + 0,       8, 1024);
  packW<<<1024, 256, 0, stream>>>((const float*)d_in[9],  wrp + 262144,  8, 1024);
  packW<<<1024, 256, 0, stream>>>((const float*)d_in[12], wrp + 524288,  8, 1024);
  packW<<<1024, 256, 0, stream>>>((const float*)d_in[15], wrp + 786432,  8, 1024);
  packW<<<1024, 256, 0, stream>>>((const float*)d_in[18], wrp + 1048576, 8, 1024);
  packW<<<1024, 256, 0, stream>>>((const float*)d_in[21], wrp + 1310720, 8, 1024);
  packW<<<1024, 256, 0, stream>>>((const float*)d_in[24], wrp + 1572864, 8, 1024);
  packW<<<1024, 256, 0, stream>>>((const float*)d_in[27], wrp + 1835008, 8, 1024);
  biasK<<<8, 256, 0, stream>>>((const float*)d_in[7],  (const float*)d_in[10], bias + 0);
  biasK<<<8, 256, 0, stream>>>((const float*)d_in[13], (const float*)d_in[16], bias + 2048);
  biasK<<<8, 256, 0, stream>>>((const float*)d_in[19], (const float*)d_in[22], bias + 4096);
  biasK<<<8, 256, 0, stream>>>((const float*)d_in[25], (const float*)d_in[28], bias + 6144);

  u16* XB0 = (u16*)(ws + O_XB0);
  u16* XB1 = (u16*)(ws + O_XB1);
  u16* xc  = (u16*)(ws + O_XC);
  float* xzb = (float*)(ws + O_XC + (size_t)C * 65536);
  int* flags = (int*)(ws + O_FLAGS);
  u16* hbuf = (u16*)(ws + O_HBUF);
  float* cbuf = (float*)(ws + O_CBUF);
  unsigned char* masks[4] = {
      (unsigned char*)(ws + O_M0), (unsigned char*)(ws + O_M1),
      (unsigned char*)(ws + O_M2), (unsigned char*)(ws + O_M3)};

  const int    Ts[4]    = {1696, 848, 424, 212};
  const int    Ks[4]    = {512, 1024, 1024, 1024};
  const size_t wkOff[4] = {0, 1048576, 3145728, 5242880};
  const size_t wrOff[4] = {0, 524288, 1048576, 1572864};
  const int    bOff[4]  = {0, 2048, 4096, 6144};
  u16* Xin[4]  = {nullptr, XB0, XB1, XB0};   // layer2 out overlays XB0 (dead by then)
  u16* Xout[4] = {XB0, XB1, XB0, nullptr};

  for (int l = 0; l < 4; ++l) {
    const int T = Ts[l], K = Ks[l];
    const int Cl = (C < T) ? C : T;
    const int R = T / Cl;
    for (int r = 0; r < R; ++r) {
      const int t0f = r * Cl, t0b = T - (r + 1) * Cl;
      const u16 *Af, *Ab;
      if (l == 0) {
        x0cK<<<2 * Cl, 256, 0, stream>>>((const float*)d_in[0], (const float*)d_in[3],
                                         (const float*)d_in[4], (const float*)d_in[2],
                                         (const float*)(ws + O_PET), xc, t0f, t0b, Cl);
        Af = xc;
        Ab = xc + (size_t)Cl * 16384;
      } else {
        Af = Xin[l] + (size_t)t0f * 32768;
        Ab = Xin[l] + (size_t)t0b * 32768;
      }
      gemmK<<<dim3(Cl * 32 / 64, 8, 2), 256, 0, stream>>>(
          Af, Ab, wk + wkOff[l], bias + bOff[l], xzb, K, Cl);
      recK<<<16, 256, 0, stream>>>(
          xzb, wrp + wrOff[l], hbuf + (size_t)l * 32768, cbuf + (size_t)l * 16384,
          flags + (size_t)l * 3392, masks[l], Xout[l],
          (l == 3) ? (float*)d_out : nullptr, T, Cl, r * Cl, (l == 3) ? 1 : 0);
    }
  }
}